// Round 3
// baseline (652.432 us; speedup 1.0000x reference)
//
#include <hip/hip_runtime.h>
#include <hip/hip_cooperative_groups.h>
#include <cmath>

namespace cg = cooperative_groups;

#define B_ 8
#define C_ 64
#define M_ 256
#define N_ 256
#define PLANE_ (M_*N_)          // 65536
#define PIX_ (B_*PLANE_)        // 524288
#define THRESH_ 0.8f
#define EPS_ 1e-5f

// sa-conv tiling (phase 2)
#define TW_ 64
#define TH_ 16
#define SAW_ (TW_+6)   // 70
#define SAH_ (TH_+6)   // 22
#define LDW_ (TW_+12)  // 76
#define LDH_ (TH_+12)  // 28
#define NTILES_ (64 * B_)   // 512

// Single cooperative kernel: phases separated by grid.sync().
// acc layout: S(64) Q(64) S1(64) Q1(64) cnt(1)
__global__ __launch_bounds__(256, 4)
void k_mega(const float* __restrict__ x, const float* __restrict__ w1,
            const float* __restrict__ wg, const float* __restrict__ bgp,
            const float* __restrict__ wb, const float* __restrict__ bbp,
            float* __restrict__ avgp, float* __restrict__ maxp,
            float* __restrict__ gammap, float* __restrict__ betap,
            float* __restrict__ acc, unsigned char* __restrict__ maskp,
            float* __restrict__ out) {
    cg::grid_group grid = cg::this_grid();
    const int tid = threadIdx.x;
    const int bid = blockIdx.x;
    const int nb  = gridDim.x;
    float* S  = acc;
    float* Q  = acc + C_;
    float* S1 = acc + 2 * C_;
    float* Q1 = acc + 3 * C_;
    int* cntp = (int*)(acc + 4 * C_);

    __shared__ float sA[LDH_][LDW_];
    __shared__ float sM[LDH_][LDW_];
    __shared__ float sSA[SAH_][SAW_];
    __shared__ float w[196];
    __shared__ float ls[4][4];
    __shared__ int bcnt;

    // ---------------- phase 1: per-pixel channel avg/max; zero accumulators ----------------
    if (bid == 0) {
        if (tid < 4 * C_) acc[tid] = 0.f;
        if (tid == 0) acc[4 * C_] = 0.f;   // cnt
    }
    for (int g = bid * 256 + tid; g < PIX_ / 4; g += nb * 256) {
        int idx4 = g * 4;
        int b = idx4 >> 16;
        int p = idx4 & (PLANE_ - 1);
        const float* xb = x + (size_t)b * C_ * PLANE_ + p;
        float4 s = make_float4(0.f, 0.f, 0.f, 0.f);
        float4 mx = make_float4(-INFINITY, -INFINITY, -INFINITY, -INFINITY);
        #pragma unroll 8
        for (int c = 0; c < C_; ++c) {
            float4 v = *(const float4*)(xb + (size_t)c * PLANE_);
            s.x += v.x; s.y += v.y; s.z += v.z; s.w += v.w;
            mx.x = fmaxf(mx.x, v.x); mx.y = fmaxf(mx.y, v.y);
            mx.z = fmaxf(mx.z, v.z); mx.w = fmaxf(mx.w, v.w);
        }
        const float r = 1.f / C_;
        s.x *= r; s.y *= r; s.z *= r; s.w *= r;
        *(float4*)(avgp + idx4) = s;
        *(float4*)(maxp + idx4) = mx;
    }
    __threadfence();
    grid.sync();

    // ---------------- phase 2: sa conv + sigmoid + gamma/beta + mask + count ----------------
    if (tid < 98) w[tid] = w1[tid];
    else if (tid < 196) w[tid] = (tid < 147) ? wg[tid - 98] : wb[tid - 147];
    float bgv = bgp[0], bbv = bbp[0];
    for (int tile = bid; tile < NTILES_; tile += nb) {
        __syncthreads();                 // LDS reuse barrier (also orders bcnt reset)
        if (tid == 0) bcnt = 0;
        int b = tile >> 6;
        int t = tile & 63;               // 16 tile-rows x 4 tile-cols per plane
        int ti0 = (t >> 2) * TH_;
        int tj0 = (t & 3) * TW_;
        const float* a = avgp + (size_t)b * PLANE_;
        const float* m = maxp + (size_t)b * PLANE_;
        // stage avg/max tile + halo 6 (zero outside plane)
        for (int idx = tid; idx < LDH_ * LDW_; idx += 256) {
            int li = idx / LDW_;
            int lj = idx - li * LDW_;
            int gi = ti0 - 6 + li, gj = tj0 - 6 + lj;
            bool ok = ((unsigned)gi < (unsigned)M_) && ((unsigned)gj < (unsigned)N_);
            int o = gi * N_ + gj;
            sA[li][lj] = ok ? a[o] : 0.f;
            sM[li][lj] = ok ? m[o] : 0.f;
        }
        __syncthreads();
        // sa_map on tile + halo 3; zero outside plane (conv zero-pads sa_map itself)
        for (int idx = tid; idx < SAH_ * SAW_; idx += 256) {
            int si = idx / SAW_;
            int sj = idx - si * SAW_;
            int gi = ti0 - 3 + si, gj = tj0 - 3 + sj;
            float v = 0.f;
            if ((unsigned)gi < (unsigned)M_ && (unsigned)gj < (unsigned)N_) {
                float a2 = 0.f;
                #pragma unroll
                for (int dh = 0; dh < 7; ++dh)
                    #pragma unroll
                    for (int dw = 0; dw < 7; ++dw)
                        a2 += sA[si + dh][sj + dw] * w[dh * 7 + dw]
                            + sM[si + dh][sj + dw] * w[49 + dh * 7 + dw];
                v = 1.f / (1.f + expf(-a2));
            }
            sSA[si][sj] = v;
        }
        __syncthreads();
        // gamma/beta convs + mask + local count
        int lcnt = 0;
        #pragma unroll
        for (int k = 0; k < 4; ++k) {
            int p = k * 256 + tid;
            int ti = p >> 6, tj = p & 63;
            float g = 0.f, be = 0.f;
            #pragma unroll
            for (int dh = 0; dh < 7; ++dh)
                #pragma unroll
                for (int dw = 0; dw < 7; ++dw) {
                    float v = sSA[ti + dh][tj + dw];
                    g  += v * w[98 + dh * 7 + dw];
                    be += v * w[147 + dh * 7 + dw];
                }
            int idx = b * PLANE_ + (ti0 + ti) * N_ + (tj0 + tj);
            gammap[idx] = g + bgv;
            betap[idx]  = be + bbv;
            int mk = (sSA[ti + 3][tj + 3] >= THRESH_) ? 1 : 0;
            maskp[idx] = (unsigned char)mk;
            lcnt += mk;
        }
        for (int off = 32; off > 0; off >>= 1) lcnt += __shfl_down(lcnt, off, 64);
        if ((tid & 63) == 0) atomicAdd(&bcnt, lcnt);
        __syncthreads();
        if (tid == 0) atomicAdd(cntp, bcnt);
    }
    __threadfence();
    grid.sync();

    // ---------------- phase 3: per-channel sums S,Q,S1,Q1 ----------------
    for (int it = bid; it < 8 * C_ * B_; it += nb) {   // 4096 items: chunk(8) x c(64) x b(8)
        int chunk = it & 7;
        int c = (it >> 3) & 63;
        int b = it >> 9;
        const float* xp = x + ((size_t)(b * C_ + c)) * PLANE_ + chunk * 8192;
        const unsigned char* mp = maskp + (size_t)b * PLANE_ + chunk * 8192;
        float s = 0.f, q = 0.f, s1 = 0.f, q1 = 0.f;
        #pragma unroll
        for (int k = 0; k < 8; ++k) {
            int t = (k * 256 + tid) * 4;
            float4 v = *(const float4*)(xp + t);
            uchar4 mm = *(const uchar4*)(mp + t);
            float m0 = (float)mm.x, m1 = (float)mm.y, m2 = (float)mm.z, m3 = (float)mm.w;
            s  += v.x + v.y + v.z + v.w;
            q  += v.x * v.x + v.y * v.y + v.z * v.z + v.w * v.w;
            s1 += v.x * m0 + v.y * m1 + v.z * m2 + v.w * m3;
            q1 += v.x * v.x * m0 + v.y * v.y * m1 + v.z * v.z * m2 + v.w * v.w * m3;
        }
        for (int off = 32; off > 0; off >>= 1) {
            s  += __shfl_down(s, off, 64);
            q  += __shfl_down(q, off, 64);
            s1 += __shfl_down(s1, off, 64);
            q1 += __shfl_down(q1, off, 64);
        }
        int wave = tid >> 6, lane = tid & 63;
        if (lane == 0) { ls[wave][0] = s; ls[wave][1] = q; ls[wave][2] = s1; ls[wave][3] = q1; }
        __syncthreads();
        if (tid == 0) {
            float ts = 0.f, tq = 0.f, ts1 = 0.f, tq1 = 0.f;
            #pragma unroll
            for (int wv = 0; wv < 4; ++wv) { ts += ls[wv][0]; tq += ls[wv][1]; ts1 += ls[wv][2]; tq1 += ls[wv][3]; }
            atomicAdd(&S[c], ts); atomicAdd(&Q[c], tq);
            atomicAdd(&S1[c], ts1); atomicAdd(&Q1[c], tq1);
        }
        __syncthreads();                 // protect ls reuse next iteration
    }
    __threadfence();
    grid.sync();

    // ---------------- phase 4: coefficients + final elementwise ----------------
    const float P = (float)PIX_;
    int cnt1 = *cntp;
    float fc1 = (float)cnt1;
    float fc0 = P - fc1;
    float Sr1 = (cnt1 == 0) ? 1.f : fc1;
    float Sr0 = (cnt1 == PIX_) ? 1.f : fc0;
    float sq1 = sqrtf(Sr1 / P), sq0 = sqrtf(Sr0 / P);
    for (int it = bid; it < 8 * C_ * B_; it += nb) {   // 4096 items: chunk(8) x c(64) x b(8)
        int chunk = it & 7;
        int c = (it >> 3) & 63;
        int b = it >> 9;
        float Sv = S[c], Qv = Q[c], S1v = S1[c], Q1v = Q1[c];
        float S0v = Sv - S1v, Q0v = Qv - Q1v;
        float mu1 = S1v / Sr1;
        float mu0 = S0v / Sr0;
        float m1 = (S1v + fc0 * mu1) / P;
        float v1 = fmaxf((Q1v + fc0 * mu1 * mu1) / P - m1 * m1, 0.f);
        float m0 = (S0v + fc1 * mu0) / P;
        float v0 = fmaxf((Q0v + fc1 * mu0 * mu0) / P - m0 * m0, 0.f);
        float A1 = rsqrtf(v1 + EPS_) * sq1;
        float A0 = rsqrtf(v0 + EPS_) * sq0;
        float B1 = (mu1 - m1) * A1;
        float B0 = (mu0 - m0) * A0;
        float ma = A1, mb = -m1 * A1 + B0;   // masked:   x*A1 - m1*A1 + B0
        float ua = A0, ub = -m0 * A0 + B1;   // unmasked: x*A0 - m0*A0 + B1
        size_t cbase = ((size_t)(b * C_ + c)) * PLANE_ + chunk * 8192;
        int pbase = b * PLANE_ + chunk * 8192;
        #pragma unroll
        for (int k = 0; k < 8; ++k) {
            int t = (k * 256 + tid) * 4;
            float4 xv = *(const float4*)(x + cbase + t);
            float4 gv = *(const float4*)(gammap + pbase + t);
            float4 bv = *(const float4*)(betap + pbase + t);
            uchar4 mv = *(const uchar4*)(maskp + pbase + t);
            float4 o;
            o.x = (mv.x ? xv.x * ma + mb : xv.x * ua + ub) * (1.f + gv.x) + bv.x;
            o.y = (mv.y ? xv.y * ma + mb : xv.y * ua + ub) * (1.f + gv.y) + bv.y;
            o.z = (mv.z ? xv.z * ma + mb : xv.z * ua + ub) * (1.f + gv.z) + bv.z;
            o.w = (mv.w ? xv.w * ma + mb : xv.w * ua + ub) * (1.f + gv.w) + bv.w;
            *(float4*)(out + cbase + t) = o;
        }
    }
}

extern "C" void kernel_launch(void* const* d_in, const int* in_sizes, int n_in,
                              void* d_out, int out_size, void* d_ws, size_t ws_size,
                              hipStream_t stream) {
    const float* x  = (const float*)d_in[0];
    const float* w1 = (const float*)d_in[1];
    const float* wg = (const float*)d_in[2];
    const float* bg = (const float*)d_in[3];
    const float* wb = (const float*)d_in[4];
    const float* bb = (const float*)d_in[5];
    float* out = (float*)d_out;

    float* ws = (float*)d_ws;
    float* avgp   = ws;                       // 524288
    float* maxp   = avgp + PIX_;              // 524288
    float* gammap = maxp + PIX_;              // 524288
    float* betap  = gammap + PIX_;            // 524288
    float* acc    = betap + PIX_;             // 257 (S,Q,S1,Q1,cnt)
    unsigned char* maskp = (unsigned char*)(acc + 4 * C_ + 1);  // 524288 bytes

    // co-resident grid sizing: __launch_bounds__(256,4) guarantees >=4 blocks/CU;
    // occupancy query + cap keeps us safely within cooperative-launch limits.
    static int gridBlocks = 0;
    if (gridBlocks == 0) {
        int bpc = 0;
        hipError_t e = hipOccupancyMaxActiveBlocksPerMultiprocessor(
            &bpc, (const void*)k_mega, 256, 0);
        if (e != hipSuccess || bpc < 1) bpc = 2;
        long g = (long)bpc * 256;             // 256 CUs on MI355X
        if (g > 1024) g = 1024;
        if (g < 256) g = 256;
        gridBlocks = (int)g;
    }

    void* args[13];
    args[0]  = (void*)&x;
    args[1]  = (void*)&w1;
    args[2]  = (void*)&wg;
    args[3]  = (void*)&bg;
    args[4]  = (void*)&wb;
    args[5]  = (void*)&bb;
    args[6]  = (void*)&avgp;
    args[7]  = (void*)&maxp;
    args[8]  = (void*)&gammap;
    args[9]  = (void*)&betap;
    args[10] = (void*)&acc;
    args[11] = (void*)&maskp;
    args[12] = (void*)&out;
    hipLaunchCooperativeKernel((const void*)k_mega, dim3(gridBlocks), dim3(256),
                               args, 0, stream);
}

// Round 6
// 328.277 us; speedup vs baseline: 1.9874x; 1.9874x over previous
//
#include <hip/hip_runtime.h>
#include <cmath>

#define B_ 8
#define C_ 64
#define M_ 256
#define N_ 256
#define PLANE_ (M_*N_)          // 65536
#define PIX_ (B_*PLANE_)        // 524288
#define THRESH_ 0.8f
#define EPS_ 1e-5f

typedef float nt_f4 __attribute__((ext_vector_type(4)));   // for nontemporal stores

// ---------------- K1: per-pixel channel avg & max (vectorized x4) ----------------
// Also zeroes the 257 accumulator words (S,Q,S1,Q1,cnt) so no separate memset.
__global__ void k_avgmax(const float* __restrict__ x,
                         float* __restrict__ avgp, float* __restrict__ maxp,
                         float* __restrict__ acc) {
    if (blockIdx.x == 0) {
        if (threadIdx.x < 4 * C_) acc[threadIdx.x] = 0.f;   // S,Q,S1,Q1 (256 words)
        if (threadIdx.x == 0) acc[4 * C_] = 0.f;            // cnt (bit pattern 0)
    }
    int idx4 = (blockIdx.x * blockDim.x + threadIdx.x) * 4;   // pixel index (global, B*M*N)
    int b = idx4 >> 16;                // / PLANE_
    int p = idx4 & (PLANE_ - 1);
    const float* xb = x + (size_t)b * C_ * PLANE_ + p;
    float4 s = make_float4(0.f, 0.f, 0.f, 0.f);
    float4 mx = make_float4(-INFINITY, -INFINITY, -INFINITY, -INFINITY);
    #pragma unroll 16
    for (int c = 0; c < C_; ++c) {
        float4 v = *(const float4*)(xb + (size_t)c * PLANE_);
        s.x += v.x; s.y += v.y; s.z += v.z; s.w += v.w;
        mx.x = fmaxf(mx.x, v.x); mx.y = fmaxf(mx.y, v.y);
        mx.z = fmaxf(mx.z, v.z); mx.w = fmaxf(mx.w, v.w);
    }
    const float r = 1.f / C_;
    s.x *= r; s.y *= r; s.z *= r; s.w *= r;
    *(float4*)(avgp + idx4) = s;
    *(float4*)(maxp + idx4) = mx;
}

// ------- K2f: fused LDS-tiled sa conv + sigmoid + gamma/beta convs + mask + count -------
// Tile: TH_ x TW_ output pixels per block. sa needed on (TH_+6)x(TW_+6) (halo 3),
// avg/max needed on (TH_+12)x(TW_+12) (halo 6).
#define TW_ 64
#define TH_ 16
#define SAW_ (TW_+6)   // 70
#define SAH_ (TH_+6)   // 22
#define LDW_ (TW_+12)  // 76
#define LDH_ (TH_+12)  // 28

__global__ void k_sa_fused(const float* __restrict__ avgp, const float* __restrict__ maxp,
                           const float* __restrict__ w1,
                           const float* __restrict__ wg, const float* __restrict__ bgp,
                           const float* __restrict__ wb, const float* __restrict__ bbp,
                           float* __restrict__ gammap, float* __restrict__ betap,
                           unsigned char* __restrict__ maskp, int* __restrict__ cntp) {
    __shared__ float sA[LDH_][LDW_];
    __shared__ float sM[LDH_][LDW_];
    __shared__ float sSA[SAH_][SAW_];
    __shared__ float w[196];           // [0:98) = w1 (avg,max), [98:147) = wg, [147:196) = wb
    __shared__ int bcnt;
    int tid = threadIdx.x;
    if (tid < 98) w[tid] = w1[tid];
    else if (tid < 196) w[tid] = (tid < 147) ? wg[tid - 98] : wb[tid - 147];
    if (tid == 196) bcnt = 0;

    int tileid = blockIdx.x;                 // 64 tiles per plane (16 rows x 4 cols)
    int b = blockIdx.y;
    int ti0 = (tileid >> 2) * TH_;
    int tj0 = (tileid & 3) * TW_;
    const float* a = avgp + (size_t)b * PLANE_;
    const float* m = maxp + (size_t)b * PLANE_;

    // stage avg/max tile + halo 6 (zero-fill outside the plane = zero padding)
    for (int idx = tid; idx < LDH_ * LDW_; idx += 256) {
        int li = idx / LDW_;
        int lj = idx - li * LDW_;
        int gi = ti0 - 6 + li, gj = tj0 - 6 + lj;
        bool ok = ((unsigned)gi < (unsigned)M_) && ((unsigned)gj < (unsigned)N_);
        int o = gi * N_ + gj;
        sA[li][lj] = ok ? a[o] : 0.f;
        sM[li][lj] = ok ? m[o] : 0.f;
    }
    __syncthreads();

    // sa_map on tile + halo 3. Outside-plane sa entries must be ZERO (conv zero-pads
    // sa_map itself), not sigmoid(0).
    for (int idx = tid; idx < SAH_ * SAW_; idx += 256) {
        int si = idx / SAW_;
        int sj = idx - si * SAW_;
        int gi = ti0 - 3 + si, gj = tj0 - 3 + sj;
        float v = 0.f;
        if ((unsigned)gi < (unsigned)M_ && (unsigned)gj < (unsigned)N_) {
            float acc = 0.f;
            #pragma unroll
            for (int dh = 0; dh < 7; ++dh) {
                #pragma unroll
                for (int dw = 0; dw < 7; ++dw) {
                    acc += sA[si + dh][sj + dw] * w[dh * 7 + dw]
                         + sM[si + dh][sj + dw] * w[49 + dh * 7 + dw];
                }
            }
            v = 1.f / (1.f + expf(-acc));
        }
        sSA[si][sj] = v;
    }
    __syncthreads();

    // gamma/beta convs on the tile, mask byte, block count
    float bgv = bgp[0], bbv = bbp[0];
    int lcnt = 0;
    #pragma unroll
    for (int k = 0; k < 4; ++k) {
        int p = k * 256 + tid;
        int ti = p >> 6, tj = p & 63;
        float g = 0.f, be = 0.f;
        #pragma unroll
        for (int dh = 0; dh < 7; ++dh) {
            #pragma unroll
            for (int dw = 0; dw < 7; ++dw) {
                float v = sSA[ti + dh][tj + dw];
                g  += v * w[98 + dh * 7 + dw];
                be += v * w[147 + dh * 7 + dw];
            }
        }
        int idx = b * PLANE_ + (ti0 + ti) * N_ + (tj0 + tj);
        gammap[idx] = g + bgv;
        betap[idx]  = be + bbv;
        int mk = (sSA[ti + 3][tj + 3] >= THRESH_) ? 1 : 0;
        maskp[idx] = (unsigned char)mk;
        lcnt += mk;
    }
    for (int off = 32; off > 0; off >>= 1) lcnt += __shfl_down(lcnt, off, 64);
    if ((tid & 63) == 0) atomicAdd(&bcnt, lcnt);
    __syncthreads();
    if (tid == 0) atomicAdd(cntp, bcnt);
}

// -------- K3: per-channel sums: S, Q, S1(masked), Q1(masked) ----------
__global__ void k_sums(const float* __restrict__ x, const unsigned char* __restrict__ maskp,
                       float* __restrict__ S, float* __restrict__ Q,
                       float* __restrict__ S1, float* __restrict__ Q1) {
    int chunk = blockIdx.x;          // 8 chunks of 8192 per plane
    int c = blockIdx.y;
    int b = blockIdx.z;
    const float* xp = x + ((size_t)(b * C_ + c)) * PLANE_ + chunk * 8192;
    const unsigned char* mp = maskp + (size_t)b * PLANE_ + chunk * 8192;
    float s = 0.f, q = 0.f, s1 = 0.f, q1 = 0.f;
    #pragma unroll
    for (int k = 0; k < 8; ++k) {
        int t = (k * 256 + threadIdx.x) * 4;
        float4 v = *(const float4*)(xp + t);
        uchar4 mm = *(const uchar4*)(mp + t);
        float m0 = (float)mm.x, m1 = (float)mm.y, m2 = (float)mm.z, m3 = (float)mm.w;
        s  += v.x + v.y + v.z + v.w;
        q  += v.x * v.x + v.y * v.y + v.z * v.z + v.w * v.w;
        s1 += v.x * m0 + v.y * m1 + v.z * m2 + v.w * m3;
        q1 += v.x * v.x * m0 + v.y * v.y * m1 + v.z * v.z * m2 + v.w * v.w * m3;
    }
    for (int off = 32; off > 0; off >>= 1) {
        s  += __shfl_down(s, off, 64);
        q  += __shfl_down(q, off, 64);
        s1 += __shfl_down(s1, off, 64);
        q1 += __shfl_down(q1, off, 64);
    }
    __shared__ float ls[4][4];
    int wave = threadIdx.x >> 6, lane = threadIdx.x & 63;
    if (lane == 0) { ls[wave][0] = s; ls[wave][1] = q; ls[wave][2] = s1; ls[wave][3] = q1; }
    __syncthreads();
    if (threadIdx.x == 0) {
        float ts = 0.f, tq = 0.f, ts1 = 0.f, tq1 = 0.f;
        #pragma unroll
        for (int wv = 0; wv < 4; ++wv) { ts += ls[wv][0]; tq += ls[wv][1]; ts1 += ls[wv][2]; tq1 += ls[wv][3]; }
        atomicAdd(&S[c], ts); atomicAdd(&Q[c], tq);
        atomicAdd(&S1[c], ts1); atomicAdd(&Q1[c], tq1);
    }
}

// -------- K5: coefficients inline + final elementwise, 4 channels per block ----------
// gamma/beta/mask are per-(b,pixel) — loading them once per 4 channels cuts their
// logical read traffic 4x. out is written nontemporal (no reuse).
__global__ void k_final(const float* __restrict__ x, const unsigned char* __restrict__ maskp,
                        const float* __restrict__ gammap, const float* __restrict__ betap,
                        const float* __restrict__ S, const float* __restrict__ Q,
                        const float* __restrict__ S1, const float* __restrict__ Q1,
                        const int* __restrict__ cntp,
                        float* __restrict__ out) {
    int c0 = blockIdx.y * 4;
    int b = blockIdx.z;
    const float P = (float)PIX_;
    int cnt1 = *cntp;
    float fc1 = (float)cnt1;
    float fc0 = P - fc1;
    float Sr1 = (cnt1 == 0) ? 1.f : fc1;
    float Sr0 = (cnt1 == PIX_) ? 1.f : fc0;
    float sq1 = sqrtf(Sr1 / P), sq0 = sqrtf(Sr0 / P);
    float ma[4], mb[4], ua[4], ub[4];
    #pragma unroll
    for (int cc = 0; cc < 4; ++cc) {
        int c = c0 + cc;
        float Sv = S[c], Qv = Q[c], S1v = S1[c], Q1v = Q1[c];
        float S0v = Sv - S1v, Q0v = Qv - Q1v;
        float mu1 = S1v / Sr1;
        float mu0 = S0v / Sr0;
        float m1 = (S1v + fc0 * mu1) / P;
        float v1 = fmaxf((Q1v + fc0 * mu1 * mu1) / P - m1 * m1, 0.f);
        float m0 = (S0v + fc1 * mu0) / P;
        float v0 = fmaxf((Q0v + fc1 * mu0 * mu0) / P - m0 * m0, 0.f);
        float A1 = rsqrtf(v1 + EPS_) * sq1;
        float A0 = rsqrtf(v0 + EPS_) * sq0;
        float B1 = (mu1 - m1) * A1;
        float B0 = (mu0 - m0) * A0;
        ma[cc] = A1; mb[cc] = -m1 * A1 + B0;   // masked:   x*A1 - m1*A1 + B0
        ua[cc] = A0; ub[cc] = -m0 * A0 + B1;   // unmasked: x*A0 - m0*A0 + B1
    }

    int p0 = blockIdx.x * 1024 + threadIdx.x * 4;     // pixel within plane
    int pp = b * PLANE_ + p0;
    float4 gv = *(const float4*)(gammap + pp);
    float4 bv = *(const float4*)(betap + pp);
    uchar4 mv = *(const uchar4*)(maskp + pp);
    float4 G = make_float4(1.f + gv.x, 1.f + gv.y, 1.f + gv.z, 1.f + gv.w);
    #pragma unroll
    for (int cc = 0; cc < 4; ++cc) {
        size_t base = ((size_t)(b * C_ + c0 + cc)) * PLANE_ + p0;
        float4 xv = *(const float4*)(x + base);
        nt_f4 o;
        o.x = (mv.x ? xv.x * ma[cc] + mb[cc] : xv.x * ua[cc] + ub[cc]) * G.x + bv.x;
        o.y = (mv.y ? xv.y * ma[cc] + mb[cc] : xv.y * ua[cc] + ub[cc]) * G.y + bv.y;
        o.z = (mv.z ? xv.z * ma[cc] + mb[cc] : xv.z * ua[cc] + ub[cc]) * G.z + bv.z;
        o.w = (mv.w ? xv.w * ma[cc] + mb[cc] : xv.w * ua[cc] + ub[cc]) * G.w + bv.w;
        __builtin_nontemporal_store(o, (nt_f4*)(out + base));
    }
}

extern "C" void kernel_launch(void* const* d_in, const int* in_sizes, int n_in,
                              void* d_out, int out_size, void* d_ws, size_t ws_size,
                              hipStream_t stream) {
    const float* x  = (const float*)d_in[0];
    const float* w1 = (const float*)d_in[1];
    const float* wg = (const float*)d_in[2];
    const float* bg = (const float*)d_in[3];
    const float* wb = (const float*)d_in[4];
    const float* bb = (const float*)d_in[5];
    float* out = (float*)d_out;

    float* ws = (float*)d_ws;
    float* avgp   = ws;                       // 524288
    float* maxp   = avgp + PIX_;              // 524288
    float* gammap = maxp + PIX_;              // 524288
    float* betap  = gammap + PIX_;            // 524288
    float* S   = betap + PIX_;                // 64
    float* Q   = S + C_;                      // 64
    float* S1  = Q + C_;                      // 64
    float* Q1  = S1 + C_;                     // 64
    int*   cnt = (int*)(Q1 + C_);             // 1
    unsigned char* maskp = (unsigned char*)(cnt + 1);  // 524288 bytes

    // K1: channel avg/max (+ zero accumulators S..cnt, 257 words)
    k_avgmax<<<PIX_ / (256 * 4), 256, 0, stream>>>(x, avgp, maxp, S);
    // K2f: fused sa conv + sigmoid + gamma/beta convs + mask + count
    dim3 g2(64, B_);
    k_sa_fused<<<g2, 256, 0, stream>>>(avgp, maxp, w1, wg, bg, wb, bb,
                                       gammap, betap, maskp, cnt);
    // K3: per-channel sums
    dim3 g3(8, C_, B_);
    k_sums<<<g3, 256, 0, stream>>>(x, maskp, S, Q, S1, Q1);
    // K5: coefficients inline + final (4 channels per block)
    dim3 g5(PLANE_ / 1024, C_ / 4, B_);
    k_final<<<g5, 256, 0, stream>>>(x, maskp, gammap, betap, S, Q, S1, Q1, cnt, out);
}